// Round 7
// baseline (386.175 us; speedup 1.0000x reference)
//
#include <hip/hip_runtime.h>

#define N_NODES_C 100000
#define N_EDGES_C 800000
#define FEATS 100
#define NCLS 50
#define GENE 20000
#define SCAN_BLK 1024
#define SCAN_NBLK ((N_NODES_C + SCAN_BLK - 1) / SCAN_BLK)   // 98

// ---------------------------------------------------------------------------
// Degree count: 4 edges/thread, vectorized dst load, 4 atomics in flight
// ---------------------------------------------------------------------------
__global__ void deg_count_kernel(const int* __restrict__ dst,
                                 int* __restrict__ deg) {
    int t = blockIdx.x * blockDim.x + threadIdx.x;
    if (t >= N_EDGES_C / 4) return;
    int4 d4 = reinterpret_cast<const int4*>(dst)[t];
    atomicAdd(&deg[d4.x], 1);
    atomicAdd(&deg[d4.y], 1);
    atomicAdd(&deg[d4.z], 1);
    atomicAdd(&deg[d4.w], 1);
}

// ---------------------------------------------------------------------------
// scan1: in-place inclusive scan per 1024-block + block totals
// ---------------------------------------------------------------------------
__global__ __launch_bounds__(1024) void scan1_kernel(int* __restrict__ deg,
                                                     int* __restrict__ bsum) {
    __shared__ int wsum[16];
    const int i = blockIdx.x * SCAN_BLK + threadIdx.x;
    const int lane = threadIdx.x & 63;
    const int wid = threadIdx.x >> 6;
    int v = (i < N_NODES_C) ? deg[i] : 0;
    #pragma unroll
    for (int d = 1; d < 64; d <<= 1) {
        int t = __shfl_up(v, d);
        if (lane >= d) v += t;
    }
    if (lane == 63) wsum[wid] = v;
    __syncthreads();
    if (wid == 0) {
        int s = (lane < 16) ? wsum[lane] : 0;
        #pragma unroll
        for (int d = 1; d < 16; d <<= 1) {
            int t = __shfl_up(s, d);
            if (lane >= d) s += t;
        }
        if (lane < 16) wsum[lane] = s;
    }
    __syncthreads();
    if (wid > 0) v += wsum[wid - 1];
    if (i < N_NODES_C) deg[i] = v;
    if (threadIdx.x == SCAN_BLK - 1) bsum[blockIdx.x] = v;
}

// ---------------------------------------------------------------------------
// scan3 (scan2 folded in): every block loads the 98 block sums in parallel,
// thread 0 does the 98-element exclusive prefix in LDS, then apply.
// ---------------------------------------------------------------------------
__global__ __launch_bounds__(1024) void scan3_kernel(const int* __restrict__ incl,
                                                     const int* __restrict__ bsum,
                                                     int* __restrict__ rp,
                                                     int* __restrict__ cursor) {
    __shared__ int boff[SCAN_NBLK];
    if (threadIdx.x < SCAN_NBLK) boff[threadIdx.x] = bsum[threadIdx.x];
    __syncthreads();
    if (threadIdx.x == 0) {
        int off = 0;
        #pragma unroll 1
        for (int j = 0; j < SCAN_NBLK; ++j) { int t = boff[j]; boff[j] = off; off += t; }
    }
    __syncthreads();
    int i = blockIdx.x * SCAN_BLK + threadIdx.x;
    if (i >= N_NODES_C) return;
    int v = incl[i] + boff[blockIdx.x];
    rp[i + 1] = v;
    cursor[i + 1] = v;
    if (i == 0) { rp[0] = 0; cursor[0] = 0; }
}

// ---------------------------------------------------------------------------
// CSR fill v2: 4 edges/thread. Vectorized sequential loads; 8 node_ids
// gathers, 4 alpha gathers, 4 atomics, 4 scattered stores — all independent.
// ---------------------------------------------------------------------------
__global__ void csr_fill_kernel(const int* __restrict__ node_ids,
                                const int* __restrict__ src,
                                const int* __restrict__ dst,
                                const float* __restrict__ ew,
                                const float* __restrict__ alpha,
                                int* __restrict__ cursor,
                                int2* __restrict__ csr) {
    int t = blockIdx.x * blockDim.x + threadIdx.x;
    if (t >= N_EDGES_C / 4) return;
    int4   s4 = reinterpret_cast<const int4*>(src)[t];
    int4   d4 = reinterpret_cast<const int4*>(dst)[t];
    float4 w4 = reinterpret_cast<const float4*>(ew)[t];

    int s[4] = {s4.x, s4.y, s4.z, s4.w};
    int d[4] = {d4.x, d4.y, d4.z, d4.w};
    float we[4] = {w4.x, w4.y, w4.z, w4.w};

    int sid[4], did[4];
    #pragma unroll
    for (int i = 0; i < 4; ++i) sid[i] = node_ids[s[i]];
    #pragma unroll
    for (int i = 0; i < 4; ++i) did[i] = node_ids[d[i]];

    float sc[4];
    #pragma unroll
    for (int i = 0; i < 4; ++i) {
        int idx = GENE + 1;                              // cell-cell
        if (sid[i] >= 0 && did[i] < 0) idx = sid[i];     // gene -> cell
        else if (did[i] >= 0 && sid[i] < 0) idx = did[i];// cell -> gene
        else if (did[i] >= 0 && sid[i] >= 0) idx = GENE; // gene -> gene
        sc[i] = alpha[idx] * we[i];
    }
    int pos[4];
    #pragma unroll
    for (int i = 0; i < 4; ++i) pos[i] = atomicAdd(&cursor[d[i]], 1);
    #pragma unroll
    for (int i = 0; i < 4; ++i) csr[pos[i]] = make_int2(s[i], __float_as_int(sc[i]));
}

// ---------------------------------------------------------------------------
// Aggregation v5: 4 nodes per wave (16-lane groups). Each lane covers two
// float4 slots (sl and sl+16, clamped to 24) of the 100-float row.
// 4-deep clamped unroll -> 32 independent row loads in flight per wave.
// Zero-weight fmaf on the clamped tail (exact no-op, order-preserving).
// ---------------------------------------------------------------------------
__global__ __launch_bounds__(256) void aggregate_kernel(
        const float* __restrict__ hin,
        const int* __restrict__ rp,
        const int2* __restrict__ csr,
        float* __restrict__ neigh) {
    const int node = (blockIdx.x * 256 + threadIdx.x) >> 4;
    const int sl = threadIdx.x & 15;
    const int slotA = sl;                       // float4 slots 0..15
    const int slotB = (sl + 16 <= 24) ? sl + 16 : 24;   // slots 16..24 (clamped)
    if (node >= N_NODES_C) return;
    const int beg = rp[node];
    const int end = rp[node + 1];
    float4 aA = make_float4(0.f, 0.f, 0.f, 0.f);
    float4 aB = make_float4(0.f, 0.f, 0.f, 0.f);
    for (int k = beg; k < end; k += 4) {
        const int k1 = min(k + 1, end - 1);
        const int k2 = min(k + 2, end - 1);
        const int k3 = min(k + 3, end - 1);
        int2 e0 = csr[k];
        int2 e1 = csr[k1];
        int2 e2 = csr[k2];
        int2 e3 = csr[k3];
        const float4* r0 = (const float4*)(hin + (size_t)e0.x * FEATS);
        const float4* r1 = (const float4*)(hin + (size_t)e1.x * FEATS);
        const float4* r2 = (const float4*)(hin + (size_t)e2.x * FEATS);
        const float4* r3 = (const float4*)(hin + (size_t)e3.x * FEATS);
        float4 xA0 = r0[slotA], xB0 = r0[slotB];
        float4 xA1 = r1[slotA], xB1 = r1[slotB];
        float4 xA2 = r2[slotA], xB2 = r2[slotB];
        float4 xA3 = r3[slotA], xB3 = r3[slotB];
        float w0 = __int_as_float(e0.y);
        float w1 = (k + 1 < end) ? __int_as_float(e1.y) : 0.0f;
        float w2 = (k + 2 < end) ? __int_as_float(e2.y) : 0.0f;
        float w3 = (k + 3 < end) ? __int_as_float(e3.y) : 0.0f;
        aA.x = fmaf(xA0.x, w0, aA.x); aA.y = fmaf(xA0.y, w0, aA.y);
        aA.z = fmaf(xA0.z, w0, aA.z); aA.w = fmaf(xA0.w, w0, aA.w);
        aB.x = fmaf(xB0.x, w0, aB.x); aB.y = fmaf(xB0.y, w0, aB.y);
        aB.z = fmaf(xB0.z, w0, aB.z); aB.w = fmaf(xB0.w, w0, aB.w);
        aA.x = fmaf(xA1.x, w1, aA.x); aA.y = fmaf(xA1.y, w1, aA.y);
        aA.z = fmaf(xA1.z, w1, aA.z); aA.w = fmaf(xA1.w, w1, aA.w);
        aB.x = fmaf(xB1.x, w1, aB.x); aB.y = fmaf(xB1.y, w1, aB.y);
        aB.z = fmaf(xB1.z, w1, aB.z); aB.w = fmaf(xB1.w, w1, aB.w);
        aA.x = fmaf(xA2.x, w2, aA.x); aA.y = fmaf(xA2.y, w2, aA.y);
        aA.z = fmaf(xA2.z, w2, aA.z); aA.w = fmaf(xA2.w, w2, aA.w);
        aB.x = fmaf(xB2.x, w2, aB.x); aB.y = fmaf(xB2.y, w2, aB.y);
        aB.z = fmaf(xB2.z, w2, aB.z); aB.w = fmaf(xB2.w, w2, aB.w);
        aA.x = fmaf(xA3.x, w3, aA.x); aA.y = fmaf(xA3.y, w3, aA.y);
        aA.z = fmaf(xA3.z, w3, aA.z); aA.w = fmaf(xA3.w, w3, aA.w);
        aB.x = fmaf(xB3.x, w3, aB.x); aB.y = fmaf(xB3.y, w3, aB.y);
        aB.z = fmaf(xB3.z, w3, aB.z); aB.w = fmaf(xB3.w, w3, aB.w);
    }
    const float invd = (end > beg) ? 1.0f / (float)(end - beg) : 0.0f;
    float4* nr = (float4*)(neigh + (size_t)node * FEATS);
    nr[slotA] = make_float4(aA.x * invd, aA.y * invd, aA.z * invd, aA.w * invd);
    if (sl + 16 <= 24) {
        nr[sl + 16] = make_float4(aB.x * invd, aB.y * invd, aB.z * invd, aB.w * invd);
    }
}

// ---------------------------------------------------------------------------
// Dense: one 32-row tile per block (grid = N/32 = 3125). 256 threads.
// (round-4 proven, unchanged)
// ---------------------------------------------------------------------------
template <int NOUT, bool RELU>
__global__ __launch_bounds__(256) void dense32_kernel(
        const float* __restrict__ in,
        const float* __restrict__ W,
        const float* __restrict__ b,
        float* __restrict__ out) {
    constexpr int RPT   = (NOUT == 100) ? 16 : 8;
    constexpr int JMASK = (NOUT == 100) ? 127 : 63;
    constexpr int GS    = (NOUT == 100) ? 7 : 6;

    __shared__ float rows[32][FEATS];
    const int tid = threadIdx.x;
    const int n0 = blockIdx.x * 32;
    const int j = tid & JMASK;
    const int grp = tid >> GS;

    for (int i = tid; i < 32 * (FEATS / 4); i += 256) {
        int r = i / (FEATS / 4);
        int k4 = i - r * (FEATS / 4);
        float4 v = reinterpret_cast<const float4*>(in + (size_t)(n0 + r) * FEATS)[k4];
        *reinterpret_cast<float4*>(&rows[r][k4 * 4]) = v;
    }

    float w[FEATS];
    float bias = 0.0f;
    if (j < NOUT) {
        bias = b[j];
        #pragma unroll
        for (int k4 = 0; k4 < FEATS / 4; ++k4) {
            float4 v = reinterpret_cast<const float4*>(W + (size_t)j * FEATS)[k4];
            w[4 * k4 + 0] = v.x;
            w[4 * k4 + 1] = v.y;
            w[4 * k4 + 2] = v.z;
            w[4 * k4 + 3] = v.w;
        }
    }
    __syncthreads();

    if (j < NOUT) {
        float acc[RPT];
        #pragma unroll
        for (int r = 0; r < RPT; ++r) acc[r] = bias;
        #pragma unroll
        for (int k4 = 0; k4 < FEATS / 4; ++k4) {
            const float wx = w[4 * k4 + 0];
            const float wy = w[4 * k4 + 1];
            const float wz = w[4 * k4 + 2];
            const float ww = w[4 * k4 + 3];
            #pragma unroll
            for (int r = 0; r < RPT; ++r) {
                float4 hv = *reinterpret_cast<const float4*>(&rows[grp * RPT + r][4 * k4]);
                acc[r] = fmaf(hv.x, wx, acc[r]);
                acc[r] = fmaf(hv.y, wy, acc[r]);
                acc[r] = fmaf(hv.z, wz, acc[r]);
                acc[r] = fmaf(hv.w, ww, acc[r]);
            }
        }
        #pragma unroll
        for (int r = 0; r < RPT; ++r) {
            float v = RELU ? fmaxf(acc[r], 0.0f) : acc[r];
            out[(size_t)(n0 + grp * RPT + r) * NOUT + j] = v;
        }
    }
}

// ---------------------------------------------------------------------------
extern "C" void kernel_launch(void* const* d_in, const int* in_sizes, int n_in,
                              void* d_out, int out_size, void* d_ws, size_t ws_size,
                              hipStream_t stream) {
    const float* features = (const float*)d_in[0];
    const int*   node_ids = (const int*)d_in[1];
    const int*   src      = (const int*)d_in[2];
    const int*   dst      = (const int*)d_in[3];
    const float* ew       = (const float*)d_in[4];
    const float* alpha    = (const float*)d_in[5];
    const float* W1       = (const float*)d_in[6];
    const float* b1       = (const float*)d_in[7];
    const float* W2       = (const float*)d_in[8];
    const float* b2       = (const float*)d_in[9];
    const float* lin_w    = (const float*)d_in[10];
    const float* lin_b    = (const float*)d_in[11];
    float* out = (float*)d_out;

    char* ws = (char*)d_ws;
    size_t off = 0;
    auto alloc = [&](size_t bytes) {
        void* p = ws + off;
        off += (bytes + 255) & ~(size_t)255;
        return p;
    };
    int*  deg    = (int*)alloc((size_t)N_NODES_C * 4);
    int*  bsum   = (int*)alloc((size_t)SCAN_NBLK * 4);
    int*  rp     = (int*)alloc((size_t)(N_NODES_C + 1) * 4);
    int*  cursor = (int*)alloc((size_t)(N_NODES_C + 1) * 4);
    int2* csr    = (int2*)alloc((size_t)N_EDGES_C * 8);
    float* neigh = (float*)alloc((size_t)N_NODES_C * FEATS * 4);
    float* h     = (float*)alloc((size_t)N_NODES_C * FEATS * 4);
    (void)ws_size;

    // --- CSR build ---
    hipMemsetAsync(deg, 0, (size_t)N_NODES_C * 4, stream);
    deg_count_kernel<<<(N_EDGES_C / 4 + 255) / 256, 256, 0, stream>>>(dst, deg);
    scan1_kernel<<<SCAN_NBLK, SCAN_BLK, 0, stream>>>(deg, bsum);
    scan3_kernel<<<SCAN_NBLK, SCAN_BLK, 0, stream>>>(deg, bsum, rp, cursor);
    csr_fill_kernel<<<(N_EDGES_C / 4 + 255) / 256, 256, 0, stream>>>(
        node_ids, src, dst, ew, alpha, cursor, csr);

    // --- Layer 1 ---
    aggregate_kernel<<<(N_NODES_C * 16 + 255) / 256, 256, 0, stream>>>(features, rp, csr, neigh);
    dense32_kernel<FEATS, true><<<N_NODES_C / 32, 256, 0, stream>>>(neigh, W1, b1, h);

    // --- Layer 2 ---
    aggregate_kernel<<<(N_NODES_C * 16 + 255) / 256, 256, 0, stream>>>(h, rp, csr, neigh);
    dense32_kernel<FEATS, true><<<N_NODES_C / 32, 256, 0, stream>>>(neigh, W2, b2, h);

    // --- Classifier ---
    dense32_kernel<NCLS, false><<<N_NODES_C / 32, 256, 0, stream>>>(h, lin_w, lin_b, out);
}

// Round 8
// 382.555 us; speedup vs baseline: 1.0095x; 1.0095x over previous
//
#include <hip/hip_runtime.h>

#define N_NODES_C 100000
#define N_EDGES_C 800000
#define FEATS 100
#define NCLS 50
#define GENE 20000
#define SCAN_BLK 1024
#define SCAN_NBLK ((N_NODES_C + SCAN_BLK - 1) / SCAN_BLK)   // 98

// ---------------------------------------------------------------------------
// Edge prep: degree count (int atomic) + per-edge scale, coalesced write.
// The node_ids/alpha gathers hide under the atomic latency.
// ---------------------------------------------------------------------------
__global__ void edge_prep_kernel(const int* __restrict__ node_ids,
                                 const int* __restrict__ src,
                                 const int* __restrict__ dst,
                                 const float* __restrict__ ew,
                                 const float* __restrict__ alpha,
                                 int* __restrict__ deg,
                                 float* __restrict__ scale) {
    int e = blockIdx.x * blockDim.x + threadIdx.x;
    if (e >= N_EDGES_C) return;
    int s = src[e];
    int d = dst[e];
    atomicAdd(&deg[d], 1);
    int sid = node_ids[s];
    int did = node_ids[d];
    int idx = GENE + 1;                        // cell-cell
    if (sid >= 0 && did < 0) idx = sid;        // gene -> cell
    else if (did >= 0 && sid < 0) idx = did;   // cell -> gene
    else if (did >= 0 && sid >= 0) idx = GENE; // gene -> gene
    scale[e] = alpha[idx] * ew[e];
}

// ---------------------------------------------------------------------------
// scan1: in-place inclusive scan per 1024-block + block totals
// ---------------------------------------------------------------------------
__global__ __launch_bounds__(1024) void scan1_kernel(int* __restrict__ deg,
                                                     int* __restrict__ bsum) {
    __shared__ int wsum[16];
    const int i = blockIdx.x * SCAN_BLK + threadIdx.x;
    const int lane = threadIdx.x & 63;
    const int wid = threadIdx.x >> 6;
    int v = (i < N_NODES_C) ? deg[i] : 0;
    #pragma unroll
    for (int d = 1; d < 64; d <<= 1) {
        int t = __shfl_up(v, d);
        if (lane >= d) v += t;
    }
    if (lane == 63) wsum[wid] = v;
    __syncthreads();
    if (wid == 0) {
        int s = (lane < 16) ? wsum[lane] : 0;
        #pragma unroll
        for (int d = 1; d < 16; d <<= 1) {
            int t = __shfl_up(s, d);
            if (lane >= d) s += t;
        }
        if (lane < 16) wsum[lane] = s;
    }
    __syncthreads();
    if (wid > 0) v += wsum[wid - 1];
    if (i < N_NODES_C) deg[i] = v;
    if (threadIdx.x == SCAN_BLK - 1) bsum[blockIdx.x] = v;
}

// ---------------------------------------------------------------------------
// scan3 (scan2 folded in): every block loads the 98 block sums, thread 0
// does the exclusive prefix in LDS, then apply.
// ---------------------------------------------------------------------------
__global__ __launch_bounds__(1024) void scan3_kernel(const int* __restrict__ incl,
                                                     const int* __restrict__ bsum,
                                                     int* __restrict__ rp,
                                                     int* __restrict__ cursor) {
    __shared__ int boff[SCAN_NBLK];
    if (threadIdx.x < SCAN_NBLK) boff[threadIdx.x] = bsum[threadIdx.x];
    __syncthreads();
    if (threadIdx.x == 0) {
        int off = 0;
        #pragma unroll 1
        for (int j = 0; j < SCAN_NBLK; ++j) { int t = boff[j]; boff[j] = off; off += t; }
    }
    __syncthreads();
    int i = blockIdx.x * SCAN_BLK + threadIdx.x;
    if (i >= N_NODES_C) return;
    int v = incl[i] + boff[blockIdx.x];
    rp[i + 1] = v;
    cursor[i + 1] = v;
    if (i == 0) { rp[0] = 0; cursor[0] = 0; }
}

// ---------------------------------------------------------------------------
// CSR fill v3: minimal chain — 3 coalesced loads, 1 atomic, 1 scatter.
// ---------------------------------------------------------------------------
__global__ void csr_fill_kernel(const int* __restrict__ src,
                                const int* __restrict__ dst,
                                const float* __restrict__ scale,
                                int* __restrict__ cursor,
                                int2* __restrict__ csr) {
    int e = blockIdx.x * blockDim.x + threadIdx.x;
    if (e >= N_EDGES_C) return;
    int s = src[e];
    int d = dst[e];
    float sc = scale[e];
    int pos = atomicAdd(&cursor[d], 1);
    csr[pos] = make_int2(s, __float_as_int(sc));
}

// ---------------------------------------------------------------------------
// Aggregation v4 (round-6 proven): 2 nodes per wave (32 lanes, float4 x 25),
// 8-deep clamped unroll -> 8 independent row loads in flight per half-wave.
// ---------------------------------------------------------------------------
__global__ __launch_bounds__(256) void aggregate_kernel(
        const float* __restrict__ hin,
        const int* __restrict__ rp,
        const int2* __restrict__ csr,
        float* __restrict__ neigh) {
    const int node = (blockIdx.x * 256 + threadIdx.x) >> 5;
    const int lane = threadIdx.x & 31;
    const int ll = (lane < FEATS / 4) ? lane : (FEATS / 4 - 1);  // clamp
    if (node >= N_NODES_C) return;
    const int beg = rp[node];
    const int end = rp[node + 1];
    float a0 = 0.0f, a1 = 0.0f, a2 = 0.0f, a3 = 0.0f;
    for (int k = beg; k < end; k += 8) {
        int kk[8];
        #pragma unroll
        for (int i = 0; i < 8; ++i) kk[i] = min(k + i, end - 1);
        int2 e0 = csr[kk[0]];
        int2 e1 = csr[kk[1]];
        int2 e2 = csr[kk[2]];
        int2 e3 = csr[kk[3]];
        int2 e4 = csr[kk[4]];
        int2 e5 = csr[kk[5]];
        int2 e6 = csr[kk[6]];
        int2 e7 = csr[kk[7]];
        float4 x0 = ((const float4*)(hin + (size_t)e0.x * FEATS))[ll];
        float4 x1 = ((const float4*)(hin + (size_t)e1.x * FEATS))[ll];
        float4 x2 = ((const float4*)(hin + (size_t)e2.x * FEATS))[ll];
        float4 x3 = ((const float4*)(hin + (size_t)e3.x * FEATS))[ll];
        float4 x4 = ((const float4*)(hin + (size_t)e4.x * FEATS))[ll];
        float4 x5 = ((const float4*)(hin + (size_t)e5.x * FEATS))[ll];
        float4 x6 = ((const float4*)(hin + (size_t)e6.x * FEATS))[ll];
        float4 x7 = ((const float4*)(hin + (size_t)e7.x * FEATS))[ll];
        float w0 = __int_as_float(e0.y);
        float w1 = (k + 1 < end) ? __int_as_float(e1.y) : 0.0f;
        float w2 = (k + 2 < end) ? __int_as_float(e2.y) : 0.0f;
        float w3 = (k + 3 < end) ? __int_as_float(e3.y) : 0.0f;
        float w4 = (k + 4 < end) ? __int_as_float(e4.y) : 0.0f;
        float w5 = (k + 5 < end) ? __int_as_float(e5.y) : 0.0f;
        float w6 = (k + 6 < end) ? __int_as_float(e6.y) : 0.0f;
        float w7 = (k + 7 < end) ? __int_as_float(e7.y) : 0.0f;
        a0 = fmaf(x0.x, w0, a0); a1 = fmaf(x0.y, w0, a1);
        a2 = fmaf(x0.z, w0, a2); a3 = fmaf(x0.w, w0, a3);
        a0 = fmaf(x1.x, w1, a0); a1 = fmaf(x1.y, w1, a1);
        a2 = fmaf(x1.z, w1, a2); a3 = fmaf(x1.w, w1, a3);
        a0 = fmaf(x2.x, w2, a0); a1 = fmaf(x2.y, w2, a1);
        a2 = fmaf(x2.z, w2, a2); a3 = fmaf(x2.w, w2, a3);
        a0 = fmaf(x3.x, w3, a0); a1 = fmaf(x3.y, w3, a1);
        a2 = fmaf(x3.z, w3, a2); a3 = fmaf(x3.w, w3, a3);
        a0 = fmaf(x4.x, w4, a0); a1 = fmaf(x4.y, w4, a1);
        a2 = fmaf(x4.z, w4, a2); a3 = fmaf(x4.w, w4, a3);
        a0 = fmaf(x5.x, w5, a0); a1 = fmaf(x5.y, w5, a1);
        a2 = fmaf(x5.z, w5, a2); a3 = fmaf(x5.w, w5, a3);
        a0 = fmaf(x6.x, w6, a0); a1 = fmaf(x6.y, w6, a1);
        a2 = fmaf(x6.z, w6, a2); a3 = fmaf(x6.w, w6, a3);
        a0 = fmaf(x7.x, w7, a0); a1 = fmaf(x7.y, w7, a1);
        a2 = fmaf(x7.z, w7, a2); a3 = fmaf(x7.w, w7, a3);
    }
    const float invd = (end > beg) ? 1.0f / (float)(end - beg) : 0.0f;
    if (lane < FEATS / 4) {
        ((float4*)(neigh + (size_t)node * FEATS))[lane] =
            make_float4(a0 * invd, a1 * invd, a2 * invd, a3 * invd);
    }
}

// ---------------------------------------------------------------------------
// dense2: 2 columns x 8 rows per thread. Each LDS b128 row-read feeds 8
// FMAs (vs 4 in dense32) -> halves LDS-issue cycles. w0+w1 = 200 VGPR,
// launch_bounds(256,2) caps at 256, no spill. Same accumulation order.
// ---------------------------------------------------------------------------
template <bool RELU>
__global__ __launch_bounds__(256, 2) void dense2_kernel(
        const float* __restrict__ in,
        const float* __restrict__ W,
        const float* __restrict__ b,
        float* __restrict__ out) {
    __shared__ float rows[32][FEATS];
    const int tid = threadIdx.x;
    const int n0 = blockIdx.x * 32;
    const int p = tid & 63;        // column pair, active p<50 -> cols 2p,2p+1
    const int g = tid >> 6;        // row group 0..3 (8 rows each)

    for (int i = tid; i < 32 * (FEATS / 4); i += 256) {
        int r = i / (FEATS / 4);
        int k4 = i - r * (FEATS / 4);
        float4 v = reinterpret_cast<const float4*>(in + (size_t)(n0 + r) * FEATS)[k4];
        *reinterpret_cast<float4*>(&rows[r][k4 * 4]) = v;
    }

    float w0[FEATS], w1[FEATS];
    float b0 = 0.0f, b1 = 0.0f;
    if (p < 50) {
        b0 = b[2 * p];
        b1 = b[2 * p + 1];
        #pragma unroll
        for (int k4 = 0; k4 < FEATS / 4; ++k4) {
            float4 v0 = reinterpret_cast<const float4*>(W + (size_t)(2 * p) * FEATS)[k4];
            float4 v1 = reinterpret_cast<const float4*>(W + (size_t)(2 * p + 1) * FEATS)[k4];
            w0[4 * k4 + 0] = v0.x; w0[4 * k4 + 1] = v0.y;
            w0[4 * k4 + 2] = v0.z; w0[4 * k4 + 3] = v0.w;
            w1[4 * k4 + 0] = v1.x; w1[4 * k4 + 1] = v1.y;
            w1[4 * k4 + 2] = v1.z; w1[4 * k4 + 3] = v1.w;
        }
    }
    __syncthreads();

    if (p < 50) {
        float a0[8], a1[8];
        #pragma unroll
        for (int r = 0; r < 8; ++r) { a0[r] = b0; a1[r] = b1; }
        #pragma unroll
        for (int k4 = 0; k4 < FEATS / 4; ++k4) {
            #pragma unroll
            for (int r = 0; r < 8; ++r) {
                float4 hv = *reinterpret_cast<const float4*>(&rows[g * 8 + r][4 * k4]);
                a0[r] = fmaf(hv.x, w0[4 * k4 + 0], a0[r]);
                a0[r] = fmaf(hv.y, w0[4 * k4 + 1], a0[r]);
                a0[r] = fmaf(hv.z, w0[4 * k4 + 2], a0[r]);
                a0[r] = fmaf(hv.w, w0[4 * k4 + 3], a0[r]);
                a1[r] = fmaf(hv.x, w1[4 * k4 + 0], a1[r]);
                a1[r] = fmaf(hv.y, w1[4 * k4 + 1], a1[r]);
                a1[r] = fmaf(hv.z, w1[4 * k4 + 2], a1[r]);
                a1[r] = fmaf(hv.w, w1[4 * k4 + 3], a1[r]);
            }
        }
        #pragma unroll
        for (int r = 0; r < 8; ++r) {
            float v0 = RELU ? fmaxf(a0[r], 0.0f) : a0[r];
            float v1 = RELU ? fmaxf(a1[r], 0.0f) : a1[r];
            *reinterpret_cast<float2*>(
                &out[(size_t)(n0 + g * 8 + r) * FEATS + 2 * p]) = make_float2(v0, v1);
        }
    }
}

// ---------------------------------------------------------------------------
// Classifier (round-4 proven dense32, NOUT=50): 4 groups x 8 rows.
// ---------------------------------------------------------------------------
__global__ __launch_bounds__(256) void cls_kernel(
        const float* __restrict__ in,
        const float* __restrict__ W,
        const float* __restrict__ b,
        float* __restrict__ out) {
    __shared__ float rows[32][FEATS];
    const int tid = threadIdx.x;
    const int n0 = blockIdx.x * 32;
    const int j = tid & 63;
    const int grp = tid >> 6;

    for (int i = tid; i < 32 * (FEATS / 4); i += 256) {
        int r = i / (FEATS / 4);
        int k4 = i - r * (FEATS / 4);
        float4 v = reinterpret_cast<const float4*>(in + (size_t)(n0 + r) * FEATS)[k4];
        *reinterpret_cast<float4*>(&rows[r][k4 * 4]) = v;
    }

    float w[FEATS];
    float bias = 0.0f;
    if (j < NCLS) {
        bias = b[j];
        #pragma unroll
        for (int k4 = 0; k4 < FEATS / 4; ++k4) {
            float4 v = reinterpret_cast<const float4*>(W + (size_t)j * FEATS)[k4];
            w[4 * k4 + 0] = v.x; w[4 * k4 + 1] = v.y;
            w[4 * k4 + 2] = v.z; w[4 * k4 + 3] = v.w;
        }
    }
    __syncthreads();

    if (j < NCLS) {
        float acc[8];
        #pragma unroll
        for (int r = 0; r < 8; ++r) acc[r] = bias;
        #pragma unroll
        for (int k4 = 0; k4 < FEATS / 4; ++k4) {
            const float wx = w[4 * k4 + 0];
            const float wy = w[4 * k4 + 1];
            const float wz = w[4 * k4 + 2];
            const float ww = w[4 * k4 + 3];
            #pragma unroll
            for (int r = 0; r < 8; ++r) {
                float4 hv = *reinterpret_cast<const float4*>(&rows[grp * 8 + r][4 * k4]);
                acc[r] = fmaf(hv.x, wx, acc[r]);
                acc[r] = fmaf(hv.y, wy, acc[r]);
                acc[r] = fmaf(hv.z, wz, acc[r]);
                acc[r] = fmaf(hv.w, ww, acc[r]);
            }
        }
        #pragma unroll
        for (int r = 0; r < 8; ++r) {
            out[(size_t)(n0 + grp * 8 + r) * NCLS + j] = acc[r];
        }
    }
}

// ---------------------------------------------------------------------------
extern "C" void kernel_launch(void* const* d_in, const int* in_sizes, int n_in,
                              void* d_out, int out_size, void* d_ws, size_t ws_size,
                              hipStream_t stream) {
    const float* features = (const float*)d_in[0];
    const int*   node_ids = (const int*)d_in[1];
    const int*   src      = (const int*)d_in[2];
    const int*   dst      = (const int*)d_in[3];
    const float* ew       = (const float*)d_in[4];
    const float* alpha    = (const float*)d_in[5];
    const float* W1       = (const float*)d_in[6];
    const float* b1       = (const float*)d_in[7];
    const float* W2       = (const float*)d_in[8];
    const float* b2       = (const float*)d_in[9];
    const float* lin_w    = (const float*)d_in[10];
    const float* lin_b    = (const float*)d_in[11];
    float* out = (float*)d_out;

    char* ws = (char*)d_ws;
    size_t off = 0;
    auto alloc = [&](size_t bytes) {
        void* p = ws + off;
        off += (bytes + 255) & ~(size_t)255;
        return p;
    };
    int*   deg    = (int*)alloc((size_t)N_NODES_C * 4);
    int*   bsum   = (int*)alloc((size_t)SCAN_NBLK * 4);
    int*   rp     = (int*)alloc((size_t)(N_NODES_C + 1) * 4);
    int*   cursor = (int*)alloc((size_t)(N_NODES_C + 1) * 4);
    float* scale  = (float*)alloc((size_t)N_EDGES_C * 4);
    int2*  csr    = (int2*)alloc((size_t)N_EDGES_C * 8);
    float* neigh  = (float*)alloc((size_t)N_NODES_C * FEATS * 4);
    float* h      = (float*)alloc((size_t)N_NODES_C * FEATS * 4);
    (void)ws_size;

    // --- CSR build ---
    hipMemsetAsync(deg, 0, (size_t)N_NODES_C * 4, stream);
    edge_prep_kernel<<<(N_EDGES_C + 255) / 256, 256, 0, stream>>>(
        node_ids, src, dst, ew, alpha, deg, scale);
    scan1_kernel<<<SCAN_NBLK, SCAN_BLK, 0, stream>>>(deg, bsum);
    scan3_kernel<<<SCAN_NBLK, SCAN_BLK, 0, stream>>>(deg, bsum, rp, cursor);
    csr_fill_kernel<<<(N_EDGES_C + 255) / 256, 256, 0, stream>>>(
        src, dst, scale, cursor, csr);

    // --- Layer 1 ---
    aggregate_kernel<<<(N_NODES_C * 32) / 256, 256, 0, stream>>>(features, rp, csr, neigh);
    dense2_kernel<true><<<N_NODES_C / 32, 256, 0, stream>>>(neigh, W1, b1, h);

    // --- Layer 2 ---
    aggregate_kernel<<<(N_NODES_C * 32) / 256, 256, 0, stream>>>(h, rp, csr, neigh);
    dense2_kernel<true><<<N_NODES_C / 32, 256, 0, stream>>>(neigh, W2, b2, h);

    // --- Classifier ---
    cls_kernel<<<N_NODES_C / 32, 256, 0, stream>>>(h, lin_w, lin_b, out);
}

// Round 9
// 373.338 us; speedup vs baseline: 1.0344x; 1.0247x over previous
//
#include <hip/hip_runtime.h>

#define N_NODES_C 100000
#define N_EDGES_C 800000
#define FEATS 100
#define NCLS 50
#define GENE 20000
#define SCAN_BLK 1024
#define SCAN_NBLK ((N_NODES_C + SCAN_BLK - 1) / SCAN_BLK)   // 98

// ---------------------------------------------------------------------------
// Edge prep: degree count (int atomic) + per-edge scale, coalesced write.
// ---------------------------------------------------------------------------
__global__ void edge_prep_kernel(const int* __restrict__ node_ids,
                                 const int* __restrict__ src,
                                 const int* __restrict__ dst,
                                 const float* __restrict__ ew,
                                 const float* __restrict__ alpha,
                                 int* __restrict__ deg,
                                 float* __restrict__ scale) {
    int e = blockIdx.x * blockDim.x + threadIdx.x;
    if (e >= N_EDGES_C) return;
    int s = src[e];
    int d = dst[e];
    atomicAdd(&deg[d], 1);
    int sid = node_ids[s];
    int did = node_ids[d];
    int idx = GENE + 1;                        // cell-cell
    if (sid >= 0 && did < 0) idx = sid;        // gene -> cell
    else if (did >= 0 && sid < 0) idx = did;   // cell -> gene
    else if (did >= 0 && sid >= 0) idx = GENE; // gene -> gene
    scale[e] = alpha[idx] * ew[e];
}

// ---------------------------------------------------------------------------
// scan1: in-place inclusive scan per 1024-block + block totals
// ---------------------------------------------------------------------------
__global__ __launch_bounds__(1024) void scan1_kernel(int* __restrict__ deg,
                                                     int* __restrict__ bsum) {
    __shared__ int wsum[16];
    const int i = blockIdx.x * SCAN_BLK + threadIdx.x;
    const int lane = threadIdx.x & 63;
    const int wid = threadIdx.x >> 6;
    int v = (i < N_NODES_C) ? deg[i] : 0;
    #pragma unroll
    for (int d = 1; d < 64; d <<= 1) {
        int t = __shfl_up(v, d);
        if (lane >= d) v += t;
    }
    if (lane == 63) wsum[wid] = v;
    __syncthreads();
    if (wid == 0) {
        int s = (lane < 16) ? wsum[lane] : 0;
        #pragma unroll
        for (int d = 1; d < 16; d <<= 1) {
            int t = __shfl_up(s, d);
            if (lane >= d) s += t;
        }
        if (lane < 16) wsum[lane] = s;
    }
    __syncthreads();
    if (wid > 0) v += wsum[wid - 1];
    if (i < N_NODES_C) deg[i] = v;
    if (threadIdx.x == SCAN_BLK - 1) bsum[blockIdx.x] = v;
}

// ---------------------------------------------------------------------------
// scan3 (scan2 folded in): every block loads the 98 block sums, thread 0
// does the exclusive prefix in LDS, then apply.
// ---------------------------------------------------------------------------
__global__ __launch_bounds__(1024) void scan3_kernel(const int* __restrict__ incl,
                                                     const int* __restrict__ bsum,
                                                     int* __restrict__ rp,
                                                     int* __restrict__ cursor) {
    __shared__ int boff[SCAN_NBLK];
    if (threadIdx.x < SCAN_NBLK) boff[threadIdx.x] = bsum[threadIdx.x];
    __syncthreads();
    if (threadIdx.x == 0) {
        int off = 0;
        #pragma unroll 1
        for (int j = 0; j < SCAN_NBLK; ++j) { int t = boff[j]; boff[j] = off; off += t; }
    }
    __syncthreads();
    int i = blockIdx.x * SCAN_BLK + threadIdx.x;
    if (i >= N_NODES_C) return;
    int v = incl[i] + boff[blockIdx.x];
    rp[i + 1] = v;
    cursor[i + 1] = v;
    if (i == 0) { rp[0] = 0; cursor[0] = 0; }
}

// ---------------------------------------------------------------------------
// CSR fill v3: minimal chain — 3 coalesced loads, 1 atomic, 1 scatter.
// ---------------------------------------------------------------------------
__global__ void csr_fill_kernel(const int* __restrict__ src,
                                const int* __restrict__ dst,
                                const float* __restrict__ scale,
                                int* __restrict__ cursor,
                                int2* __restrict__ csr) {
    int e = blockIdx.x * blockDim.x + threadIdx.x;
    if (e >= N_EDGES_C) return;
    int s = src[e];
    int d = dst[e];
    float sc = scale[e];
    int pos = atomicAdd(&cursor[d], 1);
    csr[pos] = make_int2(s, __float_as_int(sc));
}

// ---------------------------------------------------------------------------
// Aggregation v4 (round-6 proven): 2 nodes per wave (32 lanes, float4 x 25),
// 8-deep clamped unroll -> 8 independent row loads in flight per half-wave.
// ---------------------------------------------------------------------------
__global__ __launch_bounds__(256) void aggregate_kernel(
        const float* __restrict__ hin,
        const int* __restrict__ rp,
        const int2* __restrict__ csr,
        float* __restrict__ neigh) {
    const int node = (blockIdx.x * 256 + threadIdx.x) >> 5;
    const int lane = threadIdx.x & 31;
    const int ll = (lane < FEATS / 4) ? lane : (FEATS / 4 - 1);  // clamp
    if (node >= N_NODES_C) return;
    const int beg = rp[node];
    const int end = rp[node + 1];
    float a0 = 0.0f, a1 = 0.0f, a2 = 0.0f, a3 = 0.0f;
    for (int k = beg; k < end; k += 8) {
        int kk[8];
        #pragma unroll
        for (int i = 0; i < 8; ++i) kk[i] = min(k + i, end - 1);
        int2 e0 = csr[kk[0]];
        int2 e1 = csr[kk[1]];
        int2 e2 = csr[kk[2]];
        int2 e3 = csr[kk[3]];
        int2 e4 = csr[kk[4]];
        int2 e5 = csr[kk[5]];
        int2 e6 = csr[kk[6]];
        int2 e7 = csr[kk[7]];
        float4 x0 = ((const float4*)(hin + (size_t)e0.x * FEATS))[ll];
        float4 x1 = ((const float4*)(hin + (size_t)e1.x * FEATS))[ll];
        float4 x2 = ((const float4*)(hin + (size_t)e2.x * FEATS))[ll];
        float4 x3 = ((const float4*)(hin + (size_t)e3.x * FEATS))[ll];
        float4 x4 = ((const float4*)(hin + (size_t)e4.x * FEATS))[ll];
        float4 x5 = ((const float4*)(hin + (size_t)e5.x * FEATS))[ll];
        float4 x6 = ((const float4*)(hin + (size_t)e6.x * FEATS))[ll];
        float4 x7 = ((const float4*)(hin + (size_t)e7.x * FEATS))[ll];
        float w0 = __int_as_float(e0.y);
        float w1 = (k + 1 < end) ? __int_as_float(e1.y) : 0.0f;
        float w2 = (k + 2 < end) ? __int_as_float(e2.y) : 0.0f;
        float w3 = (k + 3 < end) ? __int_as_float(e3.y) : 0.0f;
        float w4 = (k + 4 < end) ? __int_as_float(e4.y) : 0.0f;
        float w5 = (k + 5 < end) ? __int_as_float(e5.y) : 0.0f;
        float w6 = (k + 6 < end) ? __int_as_float(e6.y) : 0.0f;
        float w7 = (k + 7 < end) ? __int_as_float(e7.y) : 0.0f;
        a0 = fmaf(x0.x, w0, a0); a1 = fmaf(x0.y, w0, a1);
        a2 = fmaf(x0.z, w0, a2); a3 = fmaf(x0.w, w0, a3);
        a0 = fmaf(x1.x, w1, a0); a1 = fmaf(x1.y, w1, a1);
        a2 = fmaf(x1.z, w1, a2); a3 = fmaf(x1.w, w1, a3);
        a0 = fmaf(x2.x, w2, a0); a1 = fmaf(x2.y, w2, a1);
        a2 = fmaf(x2.z, w2, a2); a3 = fmaf(x2.w, w2, a3);
        a0 = fmaf(x3.x, w3, a0); a1 = fmaf(x3.y, w3, a1);
        a2 = fmaf(x3.z, w3, a2); a3 = fmaf(x3.w, w3, a3);
        a0 = fmaf(x4.x, w4, a0); a1 = fmaf(x4.y, w4, a1);
        a2 = fmaf(x4.z, w4, a2); a3 = fmaf(x4.w, w4, a3);
        a0 = fmaf(x5.x, w5, a0); a1 = fmaf(x5.y, w5, a1);
        a2 = fmaf(x5.z, w5, a2); a3 = fmaf(x5.w, w5, a3);
        a0 = fmaf(x6.x, w6, a0); a1 = fmaf(x6.y, w6, a1);
        a2 = fmaf(x6.z, w6, a2); a3 = fmaf(x6.w, w6, a3);
        a0 = fmaf(x7.x, w7, a0); a1 = fmaf(x7.y, w7, a1);
        a2 = fmaf(x7.z, w7, a2); a3 = fmaf(x7.w, w7, a3);
    }
    const float invd = (end > beg) ? 1.0f / (float)(end - beg) : 0.0f;
    if (lane < FEATS / 4) {
        ((float4*)(neigh + (size_t)node * FEATS))[lane] =
            make_float4(a0 * invd, a1 * invd, a2 * invd, a3 * invd);
    }
}

// ---------------------------------------------------------------------------
// Dense (round-4 proven): one 32-row tile per block (grid = N/32 = 3125).
// NOUT=100: 2 groups x 16 rows, j = tid&127 (<100 active)
// NOUT=50 : 4 groups x  8 rows, j = tid&63  (<50 active)
// W row in VGPRs (~116 VGPR, no second launch-bound arg -> no spill).
// ---------------------------------------------------------------------------
template <int NOUT, bool RELU>
__global__ __launch_bounds__(256) void dense32_kernel(
        const float* __restrict__ in,
        const float* __restrict__ W,
        const float* __restrict__ b,
        float* __restrict__ out) {
    constexpr int RPT   = (NOUT == 100) ? 16 : 8;
    constexpr int JMASK = (NOUT == 100) ? 127 : 63;
    constexpr int GS    = (NOUT == 100) ? 7 : 6;

    __shared__ float rows[32][FEATS];
    const int tid = threadIdx.x;
    const int n0 = blockIdx.x * 32;
    const int j = tid & JMASK;
    const int grp = tid >> GS;

    for (int i = tid; i < 32 * (FEATS / 4); i += 256) {
        int r = i / (FEATS / 4);
        int k4 = i - r * (FEATS / 4);
        float4 v = reinterpret_cast<const float4*>(in + (size_t)(n0 + r) * FEATS)[k4];
        *reinterpret_cast<float4*>(&rows[r][k4 * 4]) = v;
    }

    float w[FEATS];
    float bias = 0.0f;
    if (j < NOUT) {
        bias = b[j];
        #pragma unroll
        for (int k4 = 0; k4 < FEATS / 4; ++k4) {
            float4 v = reinterpret_cast<const float4*>(W + (size_t)j * FEATS)[k4];
            w[4 * k4 + 0] = v.x;
            w[4 * k4 + 1] = v.y;
            w[4 * k4 + 2] = v.z;
            w[4 * k4 + 3] = v.w;
        }
    }
    __syncthreads();

    if (j < NOUT) {
        float acc[RPT];
        #pragma unroll
        for (int r = 0; r < RPT; ++r) acc[r] = bias;
        #pragma unroll
        for (int k4 = 0; k4 < FEATS / 4; ++k4) {
            const float wx = w[4 * k4 + 0];
            const float wy = w[4 * k4 + 1];
            const float wz = w[4 * k4 + 2];
            const float ww = w[4 * k4 + 3];
            #pragma unroll
            for (int r = 0; r < RPT; ++r) {
                float4 hv = *reinterpret_cast<const float4*>(&rows[grp * RPT + r][4 * k4]);
                acc[r] = fmaf(hv.x, wx, acc[r]);
                acc[r] = fmaf(hv.y, wy, acc[r]);
                acc[r] = fmaf(hv.z, wz, acc[r]);
                acc[r] = fmaf(hv.w, ww, acc[r]);
            }
        }
        #pragma unroll
        for (int r = 0; r < RPT; ++r) {
            float v = RELU ? fmaxf(acc[r], 0.0f) : acc[r];
            out[(size_t)(n0 + grp * RPT + r) * NOUT + j] = v;
        }
    }
}

// ---------------------------------------------------------------------------
extern "C" void kernel_launch(void* const* d_in, const int* in_sizes, int n_in,
                              void* d_out, int out_size, void* d_ws, size_t ws_size,
                              hipStream_t stream) {
    const float* features = (const float*)d_in[0];
    const int*   node_ids = (const int*)d_in[1];
    const int*   src      = (const int*)d_in[2];
    const int*   dst      = (const int*)d_in[3];
    const float* ew       = (const float*)d_in[4];
    const float* alpha    = (const float*)d_in[5];
    const float* W1       = (const float*)d_in[6];
    const float* b1       = (const float*)d_in[7];
    const float* W2       = (const float*)d_in[8];
    const float* b2       = (const float*)d_in[9];
    const float* lin_w    = (const float*)d_in[10];
    const float* lin_b    = (const float*)d_in[11];
    float* out = (float*)d_out;

    char* ws = (char*)d_ws;
    size_t off = 0;
    auto alloc = [&](size_t bytes) {
        void* p = ws + off;
        off += (bytes + 255) & ~(size_t)255;
        return p;
    };
    int*   deg    = (int*)alloc((size_t)N_NODES_C * 4);
    int*   bsum   = (int*)alloc((size_t)SCAN_NBLK * 4);
    int*   rp     = (int*)alloc((size_t)(N_NODES_C + 1) * 4);
    int*   cursor = (int*)alloc((size_t)(N_NODES_C + 1) * 4);
    float* scale  = (float*)alloc((size_t)N_EDGES_C * 4);
    int2*  csr    = (int2*)alloc((size_t)N_EDGES_C * 8);
    float* neigh  = (float*)alloc((size_t)N_NODES_C * FEATS * 4);
    float* h      = (float*)alloc((size_t)N_NODES_C * FEATS * 4);
    (void)ws_size;

    // --- CSR build ---
    hipMemsetAsync(deg, 0, (size_t)N_NODES_C * 4, stream);
    edge_prep_kernel<<<(N_EDGES_C + 255) / 256, 256, 0, stream>>>(
        node_ids, src, dst, ew, alpha, deg, scale);
    scan1_kernel<<<SCAN_NBLK, SCAN_BLK, 0, stream>>>(deg, bsum);
    scan3_kernel<<<SCAN_NBLK, SCAN_BLK, 0, stream>>>(deg, bsum, rp, cursor);
    csr_fill_kernel<<<(N_EDGES_C + 255) / 256, 256, 0, stream>>>(
        src, dst, scale, cursor, csr);

    // --- Layer 1 ---
    aggregate_kernel<<<(N_NODES_C * 32) / 256, 256, 0, stream>>>(features, rp, csr, neigh);
    dense32_kernel<FEATS, true><<<N_NODES_C / 32, 256, 0, stream>>>(neigh, W1, b1, h);

    // --- Layer 2 ---
    aggregate_kernel<<<(N_NODES_C * 32) / 256, 256, 0, stream>>>(h, rp, csr, neigh);
    dense32_kernel<FEATS, true><<<N_NODES_C / 32, 256, 0, stream>>>(neigh, W2, b2, h);

    // --- Classifier ---
    dense32_kernel<NCLS, false><<<N_NODES_C / 32, 256, 0, stream>>>(h, lin_w, lin_b, out);
}